// Round 9
// baseline (624.033 us; speedup 1.0000x reference)
//
#include <hip/hip_runtime.h>

#define NBANK 64
#define ACC_STRIDE (NBANK * 128) // floats per stage accumulator region

typedef _Float16 half8 __attribute__((ext_vector_type(8)));
typedef float    fx4   __attribute__((ext_vector_type(4)));

// ---------------- init (acc zero + zrow zero + grid -1, one launch) ----------------
__global__ void init_kernel(float* __restrict__ acc, int accN, _Float16* __restrict__ zrow,
                            int* __restrict__ grid, int gridN)
{
    int i = blockIdx.x * 256 + threadIdx.x;
    if (i < accN) acc[i] = 0.f;
    if (i < 64) ((float*)zrow)[i] = 0.f;   // 128 zero halves
    if (i < gridN) grid[i] = -1;
}

// ---------------- weight split + fragment re-layout (all 7 tensors, one launch) ----
// B-fragment order frag = chunk*NT + ct, chunk = k*NS + s; lane l holds
// w[k][ci = s*32 + 8*(l>>4) + j][c = ct*16 + (l&15)], j=0..8 — same ci-map as the
// A gather, so the contraction is correct for any bijective hardware K order.
// 2-term: A = f16(a); W = wh + wl  ->  a*w ≈ ah*wh + ah*wl, err ~2^-11 rel.
struct WDesc { const float* W; _Float16* H; _Float16* L; int K, CIN, COUT, base; };
struct WArgs { WDesc d[7]; int total; };

__global__ void wsplit_all_kernel(WArgs a)
{
    int t = blockIdx.x * 256 + threadIdx.x;
    if (t >= a.total) return;
    int seg = 0;
    #pragma unroll
    for (int s = 1; s < 7; ++s) if (t >= a.d[s].base) seg = s;
    const WDesc D = a.d[seg];
    int tt   = t - D.base;
    int lane = tt & 63;
    int frag = tt >> 6;
    int NT = D.COUT >> 4, NS = D.CIN >> 5;
    int ct = frag % NT;
    int s2 = (frag / NT) % NS;
    int k  = frag / (NT * NS);
    int col = ct * 16 + (lane & 15);
    int cib = s2 * 32 + ((lane >> 4) << 3);
    half8 vh, vl;
    #pragma unroll
    for (int j = 0; j < 8; ++j) {
        float w = D.W[(size_t)(k * D.CIN + cib + j) * D.COUT + col];
        _Float16 hh = (_Float16)w;
        vh[j] = hh;
        vl[j] = (_Float16)(w - (float)hh);
    }
    *(half8*)(D.H + (size_t)tt * 8) = vh;
    *(half8*)(D.L + (size_t)tt * 8) = vl;
}

// ---------------- plain f32 -> f16 convert (for input feats) ----------------
__global__ void tof16_kernel(const float* __restrict__ x, _Float16* __restrict__ h, long total)
{
    long base = ((long)blockIdx.x * 256 + threadIdx.x) * 8;
    if (base >= total) return;
    fx4 v0 = *(const fx4*)(x + base);
    fx4 v1 = *(const fx4*)(x + base + 4);
    half8 hh;
    #pragma unroll
    for (int j = 0; j < 4; ++j) { hh[j] = (_Float16)v0[j]; hh[4 + j] = (_Float16)v1[j]; }
    *(half8*)(h + base) = hh;
}

// ---------------- gather-conv via MFMA, 2-term split, LDS-shared B, chunk-skip -----
// out[m][c] = sum_{k,ci} feats[nbr[m,k]][ci] * W[k][ci][c], f32 accum.
// R8 lesson: barrier-count and pipeline-depth changes are neutral; the cost at
// ~82us (inv4) is the WORK. nbr_inv's parity construction makes ~87% of k-slots
// invalid per row, and the 128-row block UNION is only ~4-12 of 27 -> prologue
// builds a block-uniform valid-chunk list (skipped chunks contribute exact +0.0,
// bitwise-identical result), pipeline runs over the compacted list.
// Block = 4 waves x 32 rows; per chunk the block stages B fragments once into
// ping-pong LDS (reg-staged, issue-early/write-late); A-gathers pipelined one
// list-position ahead (idx queue one deeper). C/D layout (m89): col = lane&15,
// row = 4*(lane>>4)+reg. BN stats fused in the epilogue.
template <int CIN, int COUT, int K, bool DUAL>
__global__ __launch_bounds__(256) void gconv_mfma_kernel(
    const _Float16* __restrict__ fh, const int* __restrict__ nbr,
    const _Float16* __restrict__ Bh1, const _Float16* __restrict__ Bl1,
    const _Float16* __restrict__ Bh2, const _Float16* __restrict__ Bl2,
    const _Float16* __restrict__ zrow,
    float* __restrict__ out1, float* __restrict__ out2,
    float* __restrict__ sAcc1, float* __restrict__ sAcc2, int M)
{
    constexpr int NS   = CIN / 32;     // ci-chunks per neighbor
    constexpr int NT   = COUT / 16;    // 16-wide col tiles
    constexpr int NCH  = K * NS;       // total chunks
    constexpr int W2   = DUAL ? 2 : 1;
    constexpr int NARR = 2 * W2;       // {h1,l1[,h2,l2]}
    constexpr int SKB  = NARR * NT;    // KB staged per chunk (4 or 8)
    constexpr int NLD  = SKB / 4;      // fx4 stage loads per thread

    __shared__ _Float16 ldsB[2][SKB * 512];
    __shared__ int shMask;
    __shared__ int shList[NCH];
    __shared__ int shCnt;

    const int tid  = threadIdx.x;
    const int lane = tid & 63;
    const int wv   = tid >> 6;
    const int g    = lane >> 4;        // lane group (ci-chunk of 8)
    const int r    = lane & 15;        // A-row within tile / store col
    const int mb   = blockIdx.x * 128 + wv * 32;

    const int  row0 = mb + r;
    const int  row1 = mb + 16 + r;
    const bool ok0  = row0 < M;
    const bool ok1  = row1 < M;

    // ---- block-union validity mask over K neighbor slots -> compacted chunk list --
    if (tid == 0) shMask = 0;
    __syncthreads();
    {
        const int k   = tid & 31;        // slot
        const int grp = tid >> 5;        // 8 groups x 16 rows
        int bit = 0;
        if (k < K) {
            const int rbase = blockIdx.x * 128 + grp * 16;
            for (int rr = 0; rr < 16; ++rr) {
                const int row = rbase + rr;
                if (row < M && nbr[(size_t)row * K + k] >= 0) { bit = 1 << k; break; }
            }
        }
        if (bit) atomicOr(&shMask, bit);
    }
    __syncthreads();
    if (tid == 0) {
        int msk = shMask, cnt = 0;
        while (msk) {
            const int k = __ffs((unsigned)msk) - 1;
            msk &= msk - 1;
            #pragma unroll
            for (int s = 0; s < NS; ++s) shList[cnt++] = k * NS + s;
        }
        shCnt = cnt;
    }
    __syncthreads();
    const int cnt = shCnt;

    fx4 acc1[2][NT];
    fx4 acc2[DUAL ? 2 : 1][DUAL ? NT : 1];
    const fx4 zf = {0.f, 0.f, 0.f, 0.f};
    #pragma unroll
    for (int rt = 0; rt < 2; ++rt)
        #pragma unroll
        for (int ct = 0; ct < NT; ++ct) acc1[rt][ct] = zf;
    if constexpr (DUAL) {
        #pragma unroll
        for (int rt = 0; rt < 2; ++rt)
            #pragma unroll
            for (int ct = 0; ct < NT; ++ct) acc2[rt][ct] = zf;
    }

    fx4   stg[NLD];
    half8 Breg[NT][2][W2];
    half8 Aa[2], Ab[2];
    int   q0, q1;

    auto listat = [&](int i) -> int { return shList[(i < cnt) ? i : cnt - 1]; };
    auto idxld = [&](int c, int& i0, int& i1) {
        const int k = (NS == 2) ? (c >> 1) : c;
        i0 = ok0 ? nbr[(size_t)row0 * K + k] : -1;
        i1 = ok1 ? nbr[(size_t)row1 * K + k] : -1;
    };
    auto loadA = [&](half8 (&A)[2], int i0, int i1, int c) {
        const int cb = (NS == 2) ? ((c & 1) * 32) : 0;
        const _Float16* p0 = (i0 >= 0) ? fh + (size_t)i0 * CIN : zrow;
        const _Float16* p1 = (i1 >= 0) ? fh + (size_t)i1 * CIN : zrow;
        A[0] = *(const half8*)(p0 + cb + g * 8);
        A[1] = *(const half8*)(p1 + cb + g * 8);
    };
    auto stage_ld = [&](int c) {   // global -> regs (issue early)
        #pragma unroll
        for (int i = 0; i < NLD; ++i) {
            const int o   = tid * 16 + i * 4096;       // byte offset in chunk stage
            const int arr = o / (NT * 1024);
            const int oa  = o % (NT * 1024);
            const _Float16* ap = (arr == 0) ? Bh1 : (arr == 1) ? Bl1
                                : (arr == 2) ? Bh2 : Bl2;
            stg[i] = *(const fx4*)(ap + (size_t)c * (NT * 512) + oa / 2);
        }
    };
    auto stage_wr = [&](int buf) {  // vmcnt-wait stg, ds_write (late)
        #pragma unroll
        for (int i = 0; i < NLD; ++i)
            *(fx4*)(&ldsB[buf][0] + (tid * 16 + i * 4096) / 2) = stg[i];
    };
    auto loadB = [&](int buf) {
        #pragma unroll
        for (int ct = 0; ct < NT; ++ct)
            #pragma unroll
            for (int hl = 0; hl < 2; ++hl)
                #pragma unroll
                for (int w = 0; w < W2; ++w) {
                    const int arr = w * 2 + hl;
                    Breg[ct][hl][w] = *(const half8*)(&ldsB[buf][0] + (arr * NT + ct) * 512 + lane * 8);
                }
    };
    auto compute = [&](half8 (&A)[2]) {
        #pragma unroll
        for (int ct = 0; ct < NT; ++ct)
            #pragma unroll
            for (int rt = 0; rt < 2; ++rt) {
                acc1[rt][ct] = __builtin_amdgcn_mfma_f32_16x16x32_f16(A[rt], Breg[ct][0][0], acc1[rt][ct], 0, 0, 0);
                acc1[rt][ct] = __builtin_amdgcn_mfma_f32_16x16x32_f16(A[rt], Breg[ct][1][0], acc1[rt][ct], 0, 0, 0);
                if constexpr (DUAL) {
                    acc2[rt][ct] = __builtin_amdgcn_mfma_f32_16x16x32_f16(A[rt], Breg[ct][0][1], acc2[rt][ct], 0, 0, 0);
                    acc2[rt][ct] = __builtin_amdgcn_mfma_f32_16x16x32_f16(A[rt], Breg[ct][1][1], acc2[rt][ct], 0, 0, 0);
                }
            }
    };
    auto phase = [&](int i, half8 (&Acur)[2], half8 (&Anext)[2]) {
        const bool hn = (i + 1 < cnt);
        const int  cn = listat(i + 1);
        if (hn) stage_ld(cn);                    // next B -> regs (latency under MFMA)
        loadA(Anext, q0, q1, cn);                // next A -> regs
        idxld(listat(i + 2), q0, q1);            // refill idx queue
        __builtin_amdgcn_s_setprio(1);
        loadB(i & 1);                            // this chunk's B from LDS
        compute(Acur);                           // MFMA
        __builtin_amdgcn_s_setprio(0);
        if (hn) stage_wr((i + 1) & 1);           // write next B (other buffer)
        __syncthreads();                         // publish for position i+1
    };

    if (cnt > 0) {
        // ---- prologue: A(list[0]) in regs; idx queue at list[1]; B(list[0]) -> buf0
        const int c0 = shList[0];
        idxld(c0, q0, q1);
        loadA(Aa, q0, q1, c0);
        idxld(listat(1), q0, q1);
        stage_ld(c0);
        stage_wr(0);
        __syncthreads();

        int i = 0;
        while (true) {
            phase(i, Aa, Ab); if (++i >= cnt) break;
            phase(i, Ab, Aa); if (++i >= cnt) break;
        }
    }

    // ---- epilogue: C store (row = mb + rt*16 + 4*g + q, col = lane&15) ----
    #pragma unroll
    for (int rt = 0; rt < 2; ++rt)
        #pragma unroll
        for (int q = 0; q < 4; ++q) {
            const int rw = mb + rt * 16 + g * 4 + q;
            if (rw < M) {
                #pragma unroll
                for (int ct = 0; ct < NT; ++ct) {
                    out1[(size_t)rw * COUT + ct * 16 + r] = acc1[rt][ct][q];
                    if constexpr (DUAL)
                        out2[(size_t)rw * COUT + ct * 16 + r] = acc2[rt][ct][q];
                }
            }
        }

    // ---- fused BN stats: per-channel sum/sumsq, reduce over 4 lane-groups ----
    #pragma unroll
    for (int ct = 0; ct < NT; ++ct) {
        float s1 = 0.f, p1 = 0.f, s2v = 0.f, p2v = 0.f;
        #pragma unroll
        for (int rt = 0; rt < 2; ++rt)
            #pragma unroll
            for (int q = 0; q < 4; ++q) {
                const int rw = mb + rt * 16 + g * 4 + q;
                if (rw < M) {
                    float v = acc1[rt][ct][q];
                    s1 += v; p1 += v * v;
                    if constexpr (DUAL) { float u = acc2[rt][ct][q]; s2v += u; p2v += u * u; }
                }
            }
        s1 += __shfl_xor(s1, 16, 64); s1 += __shfl_xor(s1, 32, 64);
        p1 += __shfl_xor(p1, 16, 64); p1 += __shfl_xor(p1, 32, 64);
        if constexpr (DUAL) {
            s2v += __shfl_xor(s2v, 16, 64); s2v += __shfl_xor(s2v, 32, 64);
            p2v += __shfl_xor(p2v, 16, 64); p2v += __shfl_xor(p2v, 32, 64);
        }
        if (lane < 16) {
            float* a = sAcc1 + ((blockIdx.x * 4 + wv) & (NBANK - 1)) * 128;
            atomicAdd(&a[ct * 16 + lane], s1);
            atomicAdd(&a[64 + ct * 16 + lane], p1);
            if constexpr (DUAL) {
                float* b2 = sAcc2 + ((blockIdx.x * 4 + wv) & (NBANK - 1)) * 128;
                atomicAdd(&b2[ct * 16 + lane], s2v);
                atomicAdd(&b2[64 + ct * 16 + lane], p2v);
            }
        }
    }
}

// ---------------- finalize: acc banks -> scale/shift (ONE small block) -------------
// The only reader of the atomic-written acc region (R3 lesson: broadcast-reading
// dirty-atomic lines from a big grid serializes at the coherence point).
template <int C>
__global__ void finalize_kernel(const float* __restrict__ acc, const float* __restrict__ g,
                                const float* __restrict__ b, int M, float* __restrict__ sc)
{
    int c = threadIdx.x;
    if (c < C) {
        float s = 0.f, s2 = 0.f;
        #pragma unroll 8
        for (int k = 0; k < NBANK; ++k) {
            s  += acc[k * 128 + c];
            s2 += acc[k * 128 + 64 + c];
        }
        float inv  = 1.f / (float)M;
        float mean = s * inv;
        float var  = s2 * inv - mean * mean;
        float rstd = rsqrtf(var + 1e-3f);
        float scale = g[c] * rstd;
        sc[c]      = scale;
        sc[64 + c] = b[c] - mean * scale;
    }
}

// ---------------- apply: BN affine (+relu)(+add)(+f16 emit)(+stats) ----------------
// Reads clean sc[128] (plain stores, L2-hot broadcast). 8 elems/thread.
template <int C>
__global__ __launch_bounds__(256) void apply_kernel(
    const float* __restrict__ x, const float* __restrict__ sc,
    const float* __restrict__ addv, float* __restrict__ outf,
    _Float16* __restrict__ outh, float* __restrict__ statAcc, long total, int relu)
{
    __shared__ float shS[64], shS2[64];
    if (statAcc && threadIdx.x < 64) { shS[threadIdx.x] = 0.f; shS2[threadIdx.x] = 0.f; }

    float s[8], s2[8];
    #pragma unroll
    for (int j = 0; j < 8; ++j) { s[j] = 0.f; s2[j] = 0.f; }

    const long start  = ((long)blockIdx.x * 256 + threadIdx.x) * 8;
    const long stride = (long)gridDim.x * 256 * 8;
    const int  c0     = (int)(start & (C - 1));
    float sA[8], sB[8];
    #pragma unroll
    for (int j = 0; j < 8; ++j) { sA[j] = sc[c0 + j]; sB[j] = sc[64 + c0 + j]; }

    for (long base = start; base < total; base += stride) {
        fx4 v0 = *(const fx4*)(x + base);
        fx4 v1 = *(const fx4*)(x + base + 4);
        float v[8] = {v0[0], v0[1], v0[2], v0[3], v1[0], v1[1], v1[2], v1[3]};
        fx4 a0 = {0.f, 0.f, 0.f, 0.f}, a1 = {0.f, 0.f, 0.f, 0.f};
        if (addv) { a0 = *(const fx4*)(addv + base); a1 = *(const fx4*)(addv + base + 4); }
        #pragma unroll
        for (int j = 0; j < 8; ++j) {
            float w = v[j] * sA[j] + sB[j];
            if (relu) w = fmaxf(w, 0.f);
            if (addv) w += (j < 4) ? a0[j] : a1[j - 4];
            v[j] = w;
            s[j] += w; s2[j] += w * w;
        }
        if (outf) {
            *(fx4*)(outf + base)     = fx4{v[0], v[1], v[2], v[3]};
            *(fx4*)(outf + base + 4) = fx4{v[4], v[5], v[6], v[7]};
        }
        if (outh) {
            half8 hh;
            #pragma unroll
            for (int j = 0; j < 8; ++j) hh[j] = (_Float16)v[j];
            *(half8*)(outh + base) = hh;
        }
    }

    if (statAcc) {
        __syncthreads();
        #pragma unroll
        for (int j = 0; j < 8; ++j) {
            atomicAdd(&shS[c0 + j], s[j]);
            atomicAdd(&shS2[c0 + j], s2[j]);
        }
        __syncthreads();
        if (threadIdx.x < C) {
            float* a = statAcc + (blockIdx.x & (NBANK - 1)) * 128;
            atomicAdd(&a[threadIdx.x], shS[threadIdx.x]);
            atomicAdd(&a[64 + threadIdx.x], shS2[threadIdx.x]);
        }
    }
}

// ---------------- 2D projection / grid / neighbors ----------------
// Verified precision model (R5 PASS): x/y/z in f32, einsums + division in f64.
// Do not change the math.
// R6 lesson: dedup same-cell atomic runs in-block (rows spatially sorted);
// only the last thread of a run issues atomicMax (its m dominates the run).
__global__ void uv_scatter_kernel(const int* __restrict__ down, const float* __restrict__ l2r,
                                  const float* __restrict__ p2, int M,
                                  int* __restrict__ ub, int* __restrict__ vb,
                                  int* __restrict__ grid)
{
    __shared__ int shCell[256];
    const int m = blockIdx.x * 256 + threadIdx.x;
    int cell = -1;
    if (m < M) {
        int b = down[4 * m];
        float fz = (float)down[4 * m + 1];
        float fy = (float)down[4 * m + 2];
        float fx = (float)down[4 * m + 3];
        const float vs = 0.4f; // f32(0.05*8)
        float x = __fadd_rn(__fmul_rn(fx, vs), 0.2f);
        float y = __fadd_rn(__fmul_rn(fy, vs), -39.79999923706054688f); // f32(-40.0+0.2)
        float z = __fadd_rn(__fmul_rn(fz, vs), -2.79999995231628418f);  // f32(-3.0+0.2)
        double xd = (double)x, yd = (double)y, zd = (double)z;
        const float* L = l2r + b * 12;
        double r0 = (double)L[0] * xd + (double)L[1] * yd + (double)L[2]  * zd + (double)L[3];
        double r1 = (double)L[4] * xd + (double)L[5] * yd + (double)L[6]  * zd + (double)L[7];
        double r2 = (double)L[8] * xd + (double)L[9] * yd + (double)L[10] * zd + (double)L[11];
        const float* P = p2 + b * 12;
        double p0 = (double)P[0] * r0 + (double)P[1] * r1 + (double)P[2]  * r2 + (double)P[3];
        double p1 = (double)P[4] * r0 + (double)P[5] * r1 + (double)P[6]  * r2 + (double)P[7];
        double pz = (double)P[8] * r0 + (double)P[9] * r1 + (double)P[10] * r2 + (double)P[11];
        int u = (int)(p0 / pz);
        int v = (int)(p1 / pz);
        u = min(max(u, 0), 1392) >> 3;
        v = min(max(v, 0), 392) >> 3;
        ub[m] = u;
        vb[m] = v;
        cell = (b * 175 + u) * 50 + v;
    }
    shCell[threadIdx.x] = cell;
    __syncthreads();
    if (m < M) {
        const bool last = (threadIdx.x == 255) || (shCell[threadIdx.x + 1] != cell);
        if (last) atomicMax(&grid[cell], m);
    }
}

// Launder the atomic-written grid into a clean buffer so nbr2d's 1.8M broadcast
// reads are ordinary cached loads, not coherence-point reads (R3 lesson).
__global__ void grid_copy_kernel(const int* __restrict__ grid, int* __restrict__ grid2, int n)
{
    int i = blockIdx.x * 256 + threadIdx.x;
    if (i < n) grid2[i] = grid[i];
}

__global__ void nbr2d_kernel(const int* __restrict__ down, const int* __restrict__ ub,
                             const int* __restrict__ vb, const int* __restrict__ grid,
                             int* __restrict__ nb2, int M)
{
    int m = blockIdx.x * 256 + threadIdx.x;
    if (m >= M) return;
    int b = down[4 * m];
    int u = ub[m], v = vb[m];
    #pragma unroll
    for (int j = 0; j < 9; ++j) {
        int uu = u + j / 3 - 1;
        int vv = v + j % 3 - 1;
        int val = -1;
        if (uu >= 0 && uu < 175 && vv >= 0 && vv < 50) val = grid[(b * 175 + uu) * 50 + vv];
        nb2[m * 9 + j] = val;
    }
}

// ---------------- orchestration ----------------
extern "C" void kernel_launch(void* const* d_in, const int* in_sizes, int n_in,
                              void* d_out, int out_size, void* d_ws, size_t ws_size,
                              hipStream_t stream)
{
    const float* feats  = (const float*)d_in[0];
    const float* Wd1    = (const float*)d_in[1];
    const float* Wres   = (const float*)d_in[2];
    const float* Wsub2  = (const float*)d_in[3];
    const float* W2d1   = (const float*)d_in[4];
    const float* W2d2   = (const float*)d_in[5];
    const float* Wsub3  = (const float*)d_in[6];
    const float* Winv4  = (const float*)d_in[7];
    const float* bn32g  = (const float*)d_in[8];
    const float* bn32b  = (const float*)d_in[9];
    const float* bn64g  = (const float*)d_in[10];
    const float* bn64b  = (const float*)d_in[11];
    const float* l2r    = (const float*)d_in[12];
    const float* p2c    = (const float*)d_in[13];
    const int*   down   = (const int*)d_in[14];
    const int*   nbrD   = (const int*)d_in[15];
    const int*   nbrS   = (const int*)d_in[16];
    const int*   nbrI   = (const int*)d_in[17];

    const int N = in_sizes[0] / 64;
    const int M = in_sizes[14] / 4;

    char* ws = (char*)d_ws;
    size_t off = 0;
    auto alloc = [&](size_t bytes) -> void* {
        void* p = ws + off;
        off = (off + bytes + 255) & ~(size_t)255;
        return p;
    };
    float* t0    = (float*)alloc((size_t)M * 32 * 4);
    float* t1    = (float*)alloc((size_t)M * 32 * 4);
    float* t2    = (float*)alloc((size_t)M * 32 * 4);
    int*   ub    = (int*)alloc((size_t)M * 4);
    int*   vb    = (int*)alloc((size_t)M * 4);
    int*   nb2   = (int*)alloc((size_t)M * 9 * 4);
    int*   grid  = (int*)alloc((size_t)2 * 175 * 50 * 4);
    int*   grid2 = (int*)alloc((size_t)2 * 175 * 50 * 4);
    float* acc   = (float*)alloc((size_t)9 * ACC_STRIDE * 4);
    float* sc    = (float*)alloc((size_t)9 * 128 * 4);
    _Float16* zrow = (_Float16*)alloc(128 * 2);          // zeroed dummy gather row
    // f16 feature streams
    _Float16* fhh = (_Float16*)alloc((size_t)N * 64 * 2);
    _Float16* t0h = (_Float16*)alloc((size_t)M * 32 * 2);
    _Float16* t1h = (_Float16*)alloc((size_t)M * 32 * 2);
    _Float16* t2h = (_Float16*)alloc((size_t)M * 32 * 2);
    // split-f16 weight fragments (hi/lo)
    _Float16* wD1h = (_Float16*)alloc((size_t)55296 * 2);
    _Float16* wD1l = (_Float16*)alloc((size_t)55296 * 2);
    _Float16* wReh = (_Float16*)alloc((size_t)55296 * 2);
    _Float16* wRel = (_Float16*)alloc((size_t)55296 * 2);
    _Float16* wS2h = (_Float16*)alloc((size_t)27648 * 2);
    _Float16* wS2l = (_Float16*)alloc((size_t)27648 * 2);
    _Float16* w21h = (_Float16*)alloc((size_t)9216 * 2);
    _Float16* w21l = (_Float16*)alloc((size_t)9216 * 2);
    _Float16* w22h = (_Float16*)alloc((size_t)9216 * 2);
    _Float16* w22l = (_Float16*)alloc((size_t)9216 * 2);
    _Float16* wS3h = (_Float16*)alloc((size_t)27648 * 2);
    _Float16* wS3l = (_Float16*)alloc((size_t)27648 * 2);
    _Float16* wI4h = (_Float16*)alloc((size_t)55296 * 2);
    _Float16* wI4l = (_Float16*)alloc((size_t)55296 * 2);
    float* g0 = (float*)d_out; // N*64 stream computed in the output buffer

    const int accN = 9 * ACC_STRIDE;
    init_kernel<<<(accN + 255) / 256, 256, 0, stream>>>(acc, accN, zrow, grid, 17500);

    // weight split/re-layout, one launch
    WArgs wa;
    auto mkd = [](const float* W, _Float16* H, _Float16* L, int K, int CIN, int COUT, int base) {
        WDesc d; d.W = W; d.H = H; d.L = L; d.K = K; d.CIN = CIN; d.COUT = COUT; d.base = base;
        return d;
    };
    int b0 = 0;
    wa.d[0] = mkd(Wd1,   wD1h, wD1l, 27, 64, 32, b0); b0 += 27 * 64 * 32 / 8;
    wa.d[1] = mkd(Wres,  wReh, wRel, 27, 64, 32, b0); b0 += 27 * 64 * 32 / 8;
    wa.d[2] = mkd(Wsub2, wS2h, wS2l, 27, 32, 32, b0); b0 += 27 * 32 * 32 / 8;
    wa.d[3] = mkd(W2d1,  w21h, w21l,  9, 32, 32, b0); b0 += 9 * 32 * 32 / 8;
    wa.d[4] = mkd(W2d2,  w22h, w22l,  9, 32, 32, b0); b0 += 9 * 32 * 32 / 8;
    wa.d[5] = mkd(Wsub3, wS3h, wS3l, 27, 32, 32, b0); b0 += 27 * 32 * 32 / 8;
    wa.d[6] = mkd(Winv4, wI4h, wI4l, 27, 32, 64, b0); b0 += 27 * 32 * 64 / 8;
    wa.total = b0;
    wsplit_all_kernel<<<(wa.total + 255) / 256, 256, 0, stream>>>(wa);

    // input feats -> f16
    const long totF = (long)N * 64;
    tof16_kernel<<<(int)((totF / 8 + 255) / 256), 256, 0, stream>>>(feats, fhh, totF);

    const int  gT    = (M + 127) / 128;  // 128 rows/block (4 waves x 32 rows)
    const int  gTN   = (N + 127) / 128;
    const long tot32 = (long)M * 32;
    const long tot64 = (long)N * 64;
    const int  ab32  = min((int)((tot32 / 8 + 255) / 256), 2560);
    const int  ab64  = min((int)((tot64 / 8 + 255) / 256), 2560);
    const int  gM    = (M + 255) / 256;

    // stage 1: down1 + res share gathers (dual), stats fused (acc0, acc1)
    gconv_mfma_kernel<64, 32, 27, true><<<gT, 256, 0, stream>>>(
        fhh, nbrD, wD1h, wD1l, wReh, wRel, zrow, t0, t1, acc + 0 * ACC_STRIDE, acc + 1 * ACC_STRIDE, M);
    finalize_kernel<32><<<1, 64, 0, stream>>>(acc + 0 * ACC_STRIDE, bn32g + 0 * 32, bn32b + 0 * 32, M, sc + 0 * 128);
    finalize_kernel<32><<<1, 64, 0, stream>>>(acc + 1 * ACC_STRIDE, bn32g + 2 * 32, bn32b + 2 * 32, M, sc + 1 * 128);
    apply_kernel<32><<<ab32, 256, 0, stream>>>(t0, sc + 0 * 128, nullptr, nullptr, t0h, nullptr, tot32, 1); // d3a -> halves
    apply_kernel<32><<<ab32, 256, 0, stream>>>(t1, sc + 1 * 128, nullptr, t1, nullptr, nullptr, tot32, 1);  // res -> f32

    // stage 2: sub2 -> t2 (stats acc2); d3 = relu(bn)+res -> t2 f32 + halves
    gconv_mfma_kernel<32, 32, 27, false><<<gT, 256, 0, stream>>>(
        t0h, nbrS, wS2h, wS2l, nullptr, nullptr, zrow, t2, nullptr, acc + 2 * ACC_STRIDE, nullptr, M);
    finalize_kernel<32><<<1, 64, 0, stream>>>(acc + 2 * ACC_STRIDE, bn32g + 1 * 32, bn32b + 1 * 32, M, sc + 2 * 128);
    apply_kernel<32><<<ab32, 256, 0, stream>>>(t2, sc + 2 * 128, t1, t2, t2h, nullptr, tot32, 1);

    // 2D neighbor construction (dedup'd atomics; grid laundered for nbr2d)
    uv_scatter_kernel<<<gM, 256, 0, stream>>>(down, l2r, p2c, M, ub, vb, grid);
    grid_copy_kernel<<<(17500 + 255) / 256, 256, 0, stream>>>(grid, grid2, 17500);
    nbr2d_kernel<<<gM, 256, 0, stream>>>(down, ub, vb, grid2, nb2, M);

    // 2d conv 1 -> t0 (stats acc3) -> halves
    gconv_mfma_kernel<32, 32, 9, false><<<gT, 256, 0, stream>>>(
        t2h, nb2, w21h, w21l, nullptr, nullptr, zrow, t0, nullptr, acc + 3 * ACC_STRIDE, nullptr, M);
    finalize_kernel<32><<<1, 64, 0, stream>>>(acc + 3 * ACC_STRIDE, bn32g + 3 * 32, bn32b + 3 * 32, M, sc + 3 * 128);
    apply_kernel<32><<<ab32, 256, 0, stream>>>(t0, sc + 3 * 128, nullptr, nullptr, t0h, nullptr, tot32, 1);

    // 2d conv 2 -> t1 (stats acc4); t1 = relu(bn(t1)) + t2 (stats acc5)
    gconv_mfma_kernel<32, 32, 9, false><<<gT, 256, 0, stream>>>(
        t0h, nb2, w22h, w22l, nullptr, nullptr, zrow, t1, nullptr, acc + 4 * ACC_STRIDE, nullptr, M);
    finalize_kernel<32><<<1, 64, 0, stream>>>(acc + 4 * ACC_STRIDE, bn32g + 4 * 32, bn32b + 4 * 32, M, sc + 4 * 128);
    apply_kernel<32><<<ab32, 256, 0, stream>>>(t1, sc + 4 * 128, t2, t1, nullptr, acc + 5 * ACC_STRIDE, tot32, 1);
    finalize_kernel<32><<<1, 64, 0, stream>>>(acc + 5 * ACC_STRIDE, bn32g + 5 * 32, bn32b + 5 * 32, M, sc + 5 * 128);
    // bn only -> halves for sub3
    apply_kernel<32><<<ab32, 256, 0, stream>>>(t1, sc + 5 * 128, nullptr, nullptr, t1h, nullptr, tot32, 0);

    // sub3 -> t0 (stats acc6) -> halves
    gconv_mfma_kernel<32, 32, 27, false><<<gT, 256, 0, stream>>>(
        t1h, nbrS, wS3h, wS3l, nullptr, nullptr, zrow, t0, nullptr, acc + 6 * ACC_STRIDE, nullptr, M);
    finalize_kernel<32><<<1, 64, 0, stream>>>(acc + 6 * ACC_STRIDE, bn32g + 6 * 32, bn32b + 6 * 32, M, sc + 6 * 128);
    apply_kernel<32><<<ab32, 256, 0, stream>>>(t0, sc + 6 * 128, nullptr, nullptr, t0h, nullptr, tot32, 1);

    // inv4 (N rows) -> d_out (stats acc7); out2 = relu(bn) + feats (stats acc8)
    gconv_mfma_kernel<32, 64, 27, false><<<gTN, 256, 0, stream>>>(
        t0h, nbrI, wI4h, wI4l, nullptr, nullptr, zrow, g0, nullptr, acc + 7 * ACC_STRIDE, nullptr, N);
    finalize_kernel<64><<<1, 64, 0, stream>>>(acc + 7 * ACC_STRIDE, bn64g + 0 * 64, bn64b + 0 * 64, N, sc + 7 * 128);
    apply_kernel<64><<<ab64, 256, 0, stream>>>(g0, sc + 7 * 128, feats, g0, nullptr, acc + 8 * ACC_STRIDE, tot64, 1);
    finalize_kernel<64><<<1, 64, 0, stream>>>(acc + 8 * ACC_STRIDE, bn64g + 1 * 64, bn64b + 1 * 64, N, sc + 8 * 128);
    apply_kernel<64><<<ab64, 256, 0, stream>>>(g0, sc + 8 * 128, nullptr, (float*)d_out, nullptr, nullptr, tot64, 0);
}

// Round 10
// 563.385 us; speedup vs baseline: 1.1076x; 1.1076x over previous
//
#include <hip/hip_runtime.h>

#define NBANK 64
#define ACC_STRIDE (NBANK * 128) // floats per stage accumulator region

typedef _Float16 half8 __attribute__((ext_vector_type(8)));
typedef float    fx4   __attribute__((ext_vector_type(4)));

// ---------------- init (acc zero + zrow zero + grid -1, one launch) ----------------
__global__ void init_kernel(float* __restrict__ acc, int accN, _Float16* __restrict__ zrow,
                            int* __restrict__ grid, int gridN)
{
    int i = blockIdx.x * 256 + threadIdx.x;
    if (i < accN) acc[i] = 0.f;
    if (i < 64) ((float*)zrow)[i] = 0.f;   // 128 zero halves
    if (i < gridN) grid[i] = -1;
}

// ---------------- weight split + fragment re-layout (all 7 tensors, one launch) ----
// B-fragment order frag = chunk*NT + ct, chunk = k*NS + s; lane l holds
// w[k][ci = s*32 + 8*(l>>4) + j][c = ct*16 + (l&15)], j=0..8 — same ci-map as the
// A gather, so the contraction is correct for any bijective hardware K order.
// 2-term: A = f16(a); W = wh + wl  ->  a*w ≈ ah*wh + ah*wl, err ~2^-11 rel.
struct WDesc { const float* W; _Float16* H; _Float16* L; int K, CIN, COUT, base; };
struct WArgs { WDesc d[7]; int total; };

__global__ void wsplit_all_kernel(WArgs a)
{
    int t = blockIdx.x * 256 + threadIdx.x;
    if (t >= a.total) return;
    int seg = 0;
    #pragma unroll
    for (int s = 1; s < 7; ++s) if (t >= a.d[s].base) seg = s;
    const WDesc D = a.d[seg];
    int tt   = t - D.base;
    int lane = tt & 63;
    int frag = tt >> 6;
    int NT = D.COUT >> 4, NS = D.CIN >> 5;
    int ct = frag % NT;
    int s2 = (frag / NT) % NS;
    int k  = frag / (NT * NS);
    int col = ct * 16 + (lane & 15);
    int cib = s2 * 32 + ((lane >> 4) << 3);
    half8 vh, vl;
    #pragma unroll
    for (int j = 0; j < 8; ++j) {
        float w = D.W[(size_t)(k * D.CIN + cib + j) * D.COUT + col];
        _Float16 hh = (_Float16)w;
        vh[j] = hh;
        vl[j] = (_Float16)(w - (float)hh);
    }
    *(half8*)(D.H + (size_t)tt * 8) = vh;
    *(half8*)(D.L + (size_t)tt * 8) = vl;
}

// ---------------- plain f32 -> f16 convert (for input feats) ----------------
__global__ void tof16_kernel(const float* __restrict__ x, _Float16* __restrict__ h, long total)
{
    long base = ((long)blockIdx.x * 256 + threadIdx.x) * 8;
    if (base >= total) return;
    fx4 v0 = *(const fx4*)(x + base);
    fx4 v1 = *(const fx4*)(x + base + 4);
    half8 hh;
    #pragma unroll
    for (int j = 0; j < 4; ++j) { hh[j] = (_Float16)v0[j]; hh[4 + j] = (_Float16)v1[j]; }
    *(half8*)(h + base) = hh;
}

// ---------------- gather-conv via MFMA, 2-term split, LDS-shared B -----------------
// out[m][c] = sum_{k,ci} feats[nbr[m,k]][ci] * W[k][ci][c], f32 accum.
// R9 lesson: chunk-skip reverted — block union of valid k is ~full (x varies
// fastest across 128 sorted rows) and the scan prologue cost +18us.
// R10 structure: the R7 phase loop was bounded by __syncthreads' implicit
// s_waitcnt vmcnt(0), which drained the SAME-phase A-gathers (L3-latency ~500cy)
// at every one of the 27 barriers. Now: raw s_barrier with ONLY lgkmcnt(0)
// (LDS ping-pong needs ds ordering only; register A-loads need no cross-wave
// visibility) + A prefetch issued TWO phases ahead (3-slot rotation, 3-deep idx
// queue, unroll 6) so gathers ride ~2 phases of cover and never get drained.
// Same MFMA order as R7 -> bitwise-identical output.
// Block = 4 waves x 32 rows; per chunk the block stages B once into ping-pong
// LDS (reg-staged, issue-early/write-late), all 4 waves ds_read it.
// C/D layout (m89): col = lane&15, row = 4*(lane>>4)+reg. BN stats fused.
template <int CIN, int COUT, int K, bool DUAL>
__global__ __launch_bounds__(256) void gconv_mfma_kernel(
    const _Float16* __restrict__ fh, const int* __restrict__ nbr,
    const _Float16* __restrict__ Bh1, const _Float16* __restrict__ Bl1,
    const _Float16* __restrict__ Bh2, const _Float16* __restrict__ Bl2,
    const _Float16* __restrict__ zrow,
    float* __restrict__ out1, float* __restrict__ out2,
    float* __restrict__ sAcc1, float* __restrict__ sAcc2, int M)
{
    constexpr int NS   = CIN / 32;     // ci-chunks per neighbor
    constexpr int NT   = COUT / 16;    // 16-wide col tiles
    constexpr int NCH  = K * NS;       // total chunks
    constexpr int W2   = DUAL ? 2 : 1;
    constexpr int NARR = 2 * W2;       // {h1,l1[,h2,l2]}
    constexpr int SKB  = NARR * NT;    // KB staged per chunk (4 or 8)
    constexpr int NLD  = SKB / 4;      // fx4 stage loads per thread
    static_assert(NCH % 6 == 0 || NCH % 6 == 3, "tail handling assumes NCH%6 in {0,3}");

    __shared__ _Float16 ldsB[2][SKB * 512];

    const int tid  = threadIdx.x;
    const int lane = tid & 63;
    const int wv   = tid >> 6;
    const int g    = lane >> 4;        // lane group (ci-chunk of 8)
    const int r    = lane & 15;        // A-row within tile / store col
    const int mb   = blockIdx.x * 128 + wv * 32;

    const int  row0 = mb + r;
    const int  row1 = mb + 16 + r;
    const bool ok0  = row0 < M;
    const bool ok1  = row1 < M;

    fx4 acc1[2][NT];
    fx4 acc2[DUAL ? 2 : 1][DUAL ? NT : 1];
    const fx4 zf = {0.f, 0.f, 0.f, 0.f};
    #pragma unroll
    for (int rt = 0; rt < 2; ++rt)
        #pragma unroll
        for (int ct = 0; ct < NT; ++ct) acc1[rt][ct] = zf;
    if constexpr (DUAL) {
        #pragma unroll
        for (int rt = 0; rt < 2; ++rt)
            #pragma unroll
            for (int ct = 0; ct < NT; ++ct) acc2[rt][ct] = zf;
    }

    fx4   stg[NLD];
    half8 Breg[NT][2][W2];
    half8 A0[2], A1[2], A2[2];            // 3-slot A rotation (depth-2 prefetch)
    int qa0, qa1, qb0, qb1, qc0, qc1;     // 3-deep idx queue (pairs)

    auto idxld = [&](int c, int& i0, int& i1) {
        if (c < NCH) {
            const int k = (NS == 2) ? (c >> 1) : c;
            i0 = ok0 ? nbr[(size_t)row0 * K + k] : -1;
            i1 = ok1 ? nbr[(size_t)row1 * K + k] : -1;
        } else { i0 = -1; i1 = -1; }
    };
    auto loadA = [&](half8 (&A)[2], int i0, int i1, int c) {
        const int cb = (NS == 2) ? ((c & 1) * 32) : 0;
        const _Float16* p0 = (i0 >= 0) ? fh + (size_t)i0 * CIN : zrow;
        const _Float16* p1 = (i1 >= 0) ? fh + (size_t)i1 * CIN : zrow;
        A[0] = *(const half8*)(p0 + cb + g * 8);
        A[1] = *(const half8*)(p1 + cb + g * 8);
    };
    auto stage_ld = [&](int c) {   // global -> regs (issue early)
        #pragma unroll
        for (int i = 0; i < NLD; ++i) {
            const int o   = tid * 16 + i * 4096;       // byte offset in chunk stage
            const int arr = o / (NT * 1024);
            const int oa  = o % (NT * 1024);
            const _Float16* ap = (arr == 0) ? Bh1 : (arr == 1) ? Bl1
                                : (arr == 2) ? Bh2 : Bl2;
            stg[i] = *(const fx4*)(ap + (size_t)c * (NT * 512) + oa / 2);
        }
    };
    auto stage_wr = [&](int buf) {  // vmcnt(data-dep) wait on stg, ds_write (late)
        #pragma unroll
        for (int i = 0; i < NLD; ++i)
            *(fx4*)(&ldsB[buf][0] + (tid * 16 + i * 4096) / 2) = stg[i];
    };
    auto loadB = [&](int buf) {
        #pragma unroll
        for (int ct = 0; ct < NT; ++ct)
            #pragma unroll
            for (int hl = 0; hl < 2; ++hl)
                #pragma unroll
                for (int w = 0; w < W2; ++w) {
                    const int arr = w * 2 + hl;
                    Breg[ct][hl][w] = *(const half8*)(&ldsB[buf][0] + (arr * NT + ct) * 512 + lane * 8);
                }
    };
    auto compute = [&](half8 (&A)[2]) {
        #pragma unroll
        for (int ct = 0; ct < NT; ++ct)
            #pragma unroll
            for (int rt = 0; rt < 2; ++rt) {
                acc1[rt][ct] = __builtin_amdgcn_mfma_f32_16x16x32_f16(A[rt], Breg[ct][0][0], acc1[rt][ct], 0, 0, 0);
                acc1[rt][ct] = __builtin_amdgcn_mfma_f32_16x16x32_f16(A[rt], Breg[ct][1][0], acc1[rt][ct], 0, 0, 0);
                if constexpr (DUAL) {
                    acc2[rt][ct] = __builtin_amdgcn_mfma_f32_16x16x32_f16(A[rt], Breg[ct][0][1], acc2[rt][ct], 0, 0, 0);
                    acc2[rt][ct] = __builtin_amdgcn_mfma_f32_16x16x32_f16(A[rt], Breg[ct][1][1], acc2[rt][ct], 0, 0, 0);
                }
            }
    };
    // One phase: compute chunk c from Acur; stage B(c+1); issue A(c+2) into Aload
    // using idx pair (i0,i1); refill (f0,f1) with idx(c+3). Ends with raw barrier:
    // lgkmcnt(0) only — register A-gathers stay in flight across it.
    auto phase = [&](half8 (&Acur)[2], half8 (&Aload)[2], int i0, int i1,
                     int& f0, int& f1, int c, int rb, int wb) {
        const bool hn = (c + 1 < NCH);
        if (hn) stage_ld(c + 1);
        loadA(Aload, i0, i1, c + 2);
        idxld(c + 3, f0, f1);
        __builtin_amdgcn_s_setprio(1);
        loadB(rb);
        compute(Acur);
        __builtin_amdgcn_s_setprio(0);
        if (hn) stage_wr(wb);
        asm volatile("s_waitcnt lgkmcnt(0)" ::: "memory");
        __builtin_amdgcn_s_barrier();
        __builtin_amdgcn_sched_barrier(0);
    };

    // ---- prologue: A(0),A(1) in regs; idx(2) queued; B(0) staged to buf0 ----
    idxld(0, qa0, qa1);
    loadA(A0, qa0, qa1, 0);
    idxld(1, qb0, qb1);
    loadA(A1, qb0, qb1, 1);
    idxld(2, qc0, qc1);
    stage_ld(0);
    stage_wr(0);
    asm volatile("s_waitcnt lgkmcnt(0)" ::: "memory");
    __builtin_amdgcn_s_barrier();
    __builtin_amdgcn_sched_barrier(0);

    // ---- main loop: unroll 6 (A period 3 x buffer period 2), static slots ----
    int c = 0;
    for (; c + 6 <= NCH; c += 6) {
        phase(A0, A2, qc0, qc1, qa0, qa1, c + 0, 0, 1);
        phase(A1, A0, qa0, qa1, qb0, qb1, c + 1, 1, 0);
        phase(A2, A1, qb0, qb1, qc0, qc1, c + 2, 0, 1);
        phase(A0, A2, qc0, qc1, qa0, qa1, c + 3, 1, 0);
        phase(A1, A0, qa0, qa1, qb0, qb1, c + 4, 0, 1);
        phase(A2, A1, qb0, qb1, qc0, qc1, c + 5, 1, 0);
    }
    if constexpr (NCH % 6 == 3) {   // tail chunks NCH-3..NCH-1 (base ≡ 0 mod 6)
        phase(A0, A2, qc0, qc1, qa0, qa1, c + 0, 0, 1);
        phase(A1, A0, qa0, qa1, qb0, qb1, c + 1, 1, 0);
        phase(A2, A1, qb0, qb1, qc0, qc1, c + 2, 0, 1);
    }

    // ---- epilogue: C store (row = mb + rt*16 + 4*g + q, col = lane&15) ----
    #pragma unroll
    for (int rt = 0; rt < 2; ++rt)
        #pragma unroll
        for (int q = 0; q < 4; ++q) {
            const int rw = mb + rt * 16 + g * 4 + q;
            if (rw < M) {
                #pragma unroll
                for (int ct = 0; ct < NT; ++ct) {
                    out1[(size_t)rw * COUT + ct * 16 + r] = acc1[rt][ct][q];
                    if constexpr (DUAL)
                        out2[(size_t)rw * COUT + ct * 16 + r] = acc2[rt][ct][q];
                }
            }
        }

    // ---- fused BN stats: per-channel sum/sumsq, reduce over 4 lane-groups ----
    #pragma unroll
    for (int ct = 0; ct < NT; ++ct) {
        float s1 = 0.f, p1 = 0.f, s2v = 0.f, p2v = 0.f;
        #pragma unroll
        for (int rt = 0; rt < 2; ++rt)
            #pragma unroll
            for (int q = 0; q < 4; ++q) {
                const int rw = mb + rt * 16 + g * 4 + q;
                if (rw < M) {
                    float v = acc1[rt][ct][q];
                    s1 += v; p1 += v * v;
                    if constexpr (DUAL) { float u = acc2[rt][ct][q]; s2v += u; p2v += u * u; }
                }
            }
        s1 += __shfl_xor(s1, 16, 64); s1 += __shfl_xor(s1, 32, 64);
        p1 += __shfl_xor(p1, 16, 64); p1 += __shfl_xor(p1, 32, 64);
        if constexpr (DUAL) {
            s2v += __shfl_xor(s2v, 16, 64); s2v += __shfl_xor(s2v, 32, 64);
            p2v += __shfl_xor(p2v, 16, 64); p2v += __shfl_xor(p2v, 32, 64);
        }
        if (lane < 16) {
            float* a = sAcc1 + ((blockIdx.x * 4 + wv) & (NBANK - 1)) * 128;
            atomicAdd(&a[ct * 16 + lane], s1);
            atomicAdd(&a[64 + ct * 16 + lane], p1);
            if constexpr (DUAL) {
                float* b2 = sAcc2 + ((blockIdx.x * 4 + wv) & (NBANK - 1)) * 128;
                atomicAdd(&b2[ct * 16 + lane], s2v);
                atomicAdd(&b2[64 + ct * 16 + lane], p2v);
            }
        }
    }
}

// ---------------- finalize: acc banks -> scale/shift (ONE small block) -------------
// The only reader of the atomic-written acc region (R3 lesson: broadcast-reading
// dirty-atomic lines from a big grid serializes at the coherence point).
template <int C>
__global__ void finalize_kernel(const float* __restrict__ acc, const float* __restrict__ g,
                                const float* __restrict__ b, int M, float* __restrict__ sc)
{
    int c = threadIdx.x;
    if (c < C) {
        float s = 0.f, s2 = 0.f;
        #pragma unroll 8
        for (int k = 0; k < NBANK; ++k) {
            s  += acc[k * 128 + c];
            s2 += acc[k * 128 + 64 + c];
        }
        float inv  = 1.f / (float)M;
        float mean = s * inv;
        float var  = s2 * inv - mean * mean;
        float rstd = rsqrtf(var + 1e-3f);
        float scale = g[c] * rstd;
        sc[c]      = scale;
        sc[64 + c] = b[c] - mean * scale;
    }
}

// ---------------- apply: BN affine (+relu)(+add)(+f16 emit)(+stats) ----------------
// Reads clean sc[128] (plain stores, L2-hot broadcast). 8 elems/thread.
template <int C>
__global__ __launch_bounds__(256) void apply_kernel(
    const float* __restrict__ x, const float* __restrict__ sc,
    const float* __restrict__ addv, float* __restrict__ outf,
    _Float16* __restrict__ outh, float* __restrict__ statAcc, long total, int relu)
{
    __shared__ float shS[64], shS2[64];
    if (statAcc && threadIdx.x < 64) { shS[threadIdx.x] = 0.f; shS2[threadIdx.x] = 0.f; }

    float s[8], s2[8];
    #pragma unroll
    for (int j = 0; j < 8; ++j) { s[j] = 0.f; s2[j] = 0.f; }

    const long start  = ((long)blockIdx.x * 256 + threadIdx.x) * 8;
    const long stride = (long)gridDim.x * 256 * 8;
    const int  c0     = (int)(start & (C - 1));
    float sA[8], sB[8];
    #pragma unroll
    for (int j = 0; j < 8; ++j) { sA[j] = sc[c0 + j]; sB[j] = sc[64 + c0 + j]; }

    for (long base = start; base < total; base += stride) {
        fx4 v0 = *(const fx4*)(x + base);
        fx4 v1 = *(const fx4*)(x + base + 4);
        float v[8] = {v0[0], v0[1], v0[2], v0[3], v1[0], v1[1], v1[2], v1[3]};
        fx4 a0 = {0.f, 0.f, 0.f, 0.f}, a1 = {0.f, 0.f, 0.f, 0.f};
        if (addv) { a0 = *(const fx4*)(addv + base); a1 = *(const fx4*)(addv + base + 4); }
        #pragma unroll
        for (int j = 0; j < 8; ++j) {
            float w = v[j] * sA[j] + sB[j];
            if (relu) w = fmaxf(w, 0.f);
            if (addv) w += (j < 4) ? a0[j] : a1[j - 4];
            v[j] = w;
            s[j] += w; s2[j] += w * w;
        }
        if (outf) {
            *(fx4*)(outf + base)     = fx4{v[0], v[1], v[2], v[3]};
            *(fx4*)(outf + base + 4) = fx4{v[4], v[5], v[6], v[7]};
        }
        if (outh) {
            half8 hh;
            #pragma unroll
            for (int j = 0; j < 8; ++j) hh[j] = (_Float16)v[j];
            *(half8*)(outh + base) = hh;
        }
    }

    if (statAcc) {
        __syncthreads();
        #pragma unroll
        for (int j = 0; j < 8; ++j) {
            atomicAdd(&shS[c0 + j], s[j]);
            atomicAdd(&shS2[c0 + j], s2[j]);
        }
        __syncthreads();
        if (threadIdx.x < C) {
            float* a = statAcc + (blockIdx.x & (NBANK - 1)) * 128;
            atomicAdd(&a[threadIdx.x], shS[threadIdx.x]);
            atomicAdd(&a[64 + threadIdx.x], shS2[threadIdx.x]);
        }
    }
}

// ---------------- 2D projection / grid / neighbors ----------------
// Verified precision model (R5 PASS): x/y/z in f32, einsums + division in f64.
// Do not change the math.
// R6 lesson: dedup same-cell atomic runs in-block (rows spatially sorted);
// only the last thread of a run issues atomicMax (its m dominates the run).
__global__ void uv_scatter_kernel(const int* __restrict__ down, const float* __restrict__ l2r,
                                  const float* __restrict__ p2, int M,
                                  int* __restrict__ ub, int* __restrict__ vb,
                                  int* __restrict__ grid)
{
    __shared__ int shCell[256];
    const int m = blockIdx.x * 256 + threadIdx.x;
    int cell = -1;
    if (m < M) {
        int b = down[4 * m];
        float fz = (float)down[4 * m + 1];
        float fy = (float)down[4 * m + 2];
        float fx = (float)down[4 * m + 3];
        const float vs = 0.4f; // f32(0.05*8)
        float x = __fadd_rn(__fmul_rn(fx, vs), 0.2f);
        float y = __fadd_rn(__fmul_rn(fy, vs), -39.79999923706054688f); // f32(-40.0+0.2)
        float z = __fadd_rn(__fmul_rn(fz, vs), -2.79999995231628418f);  // f32(-3.0+0.2)
        double xd = (double)x, yd = (double)y, zd = (double)z;
        const float* L = l2r + b * 12;
        double r0 = (double)L[0] * xd + (double)L[1] * yd + (double)L[2]  * zd + (double)L[3];
        double r1 = (double)L[4] * xd + (double)L[5] * yd + (double)L[6]  * zd + (double)L[7];
        double r2 = (double)L[8] * xd + (double)L[9] * yd + (double)L[10] * zd + (double)L[11];
        const float* P = p2 + b * 12;
        double p0 = (double)P[0] * r0 + (double)P[1] * r1 + (double)P[2]  * r2 + (double)P[3];
        double p1 = (double)P[4] * r0 + (double)P[5] * r1 + (double)P[6]  * r2 + (double)P[7];
        double pz = (double)P[8] * r0 + (double)P[9] * r1 + (double)P[10] * r2 + (double)P[11];
        int u = (int)(p0 / pz);
        int v = (int)(p1 / pz);
        u = min(max(u, 0), 1392) >> 3;
        v = min(max(v, 0), 392) >> 3;
        ub[m] = u;
        vb[m] = v;
        cell = (b * 175 + u) * 50 + v;
    }
    shCell[threadIdx.x] = cell;
    __syncthreads();
    if (m < M) {
        const bool last = (threadIdx.x == 255) || (shCell[threadIdx.x + 1] != cell);
        if (last) atomicMax(&grid[cell], m);
    }
}

// Launder the atomic-written grid into a clean buffer so nbr2d's 1.8M broadcast
// reads are ordinary cached loads, not coherence-point reads (R3 lesson).
__global__ void grid_copy_kernel(const int* __restrict__ grid, int* __restrict__ grid2, int n)
{
    int i = blockIdx.x * 256 + threadIdx.x;
    if (i < n) grid2[i] = grid[i];
}

__global__ void nbr2d_kernel(const int* __restrict__ down, const int* __restrict__ ub,
                             const int* __restrict__ vb, const int* __restrict__ grid,
                             int* __restrict__ nb2, int M)
{
    int m = blockIdx.x * 256 + threadIdx.x;
    if (m >= M) return;
    int b = down[4 * m];
    int u = ub[m], v = vb[m];
    #pragma unroll
    for (int j = 0; j < 9; ++j) {
        int uu = u + j / 3 - 1;
        int vv = v + j % 3 - 1;
        int val = -1;
        if (uu >= 0 && uu < 175 && vv >= 0 && vv < 50) val = grid[(b * 175 + uu) * 50 + vv];
        nb2[m * 9 + j] = val;
    }
}

// ---------------- orchestration ----------------
extern "C" void kernel_launch(void* const* d_in, const int* in_sizes, int n_in,
                              void* d_out, int out_size, void* d_ws, size_t ws_size,
                              hipStream_t stream)
{
    const float* feats  = (const float*)d_in[0];
    const float* Wd1    = (const float*)d_in[1];
    const float* Wres   = (const float*)d_in[2];
    const float* Wsub2  = (const float*)d_in[3];
    const float* W2d1   = (const float*)d_in[4];
    const float* W2d2   = (const float*)d_in[5];
    const float* Wsub3  = (const float*)d_in[6];
    const float* Winv4  = (const float*)d_in[7];
    const float* bn32g  = (const float*)d_in[8];
    const float* bn32b  = (const float*)d_in[9];
    const float* bn64g  = (const float*)d_in[10];
    const float* bn64b  = (const float*)d_in[11];
    const float* l2r    = (const float*)d_in[12];
    const float* p2c    = (const float*)d_in[13];
    const int*   down   = (const int*)d_in[14];
    const int*   nbrD   = (const int*)d_in[15];
    const int*   nbrS   = (const int*)d_in[16];
    const int*   nbrI   = (const int*)d_in[17];

    const int N = in_sizes[0] / 64;
    const int M = in_sizes[14] / 4;

    char* ws = (char*)d_ws;
    size_t off = 0;
    auto alloc = [&](size_t bytes) -> void* {
        void* p = ws + off;
        off = (off + bytes + 255) & ~(size_t)255;
        return p;
    };
    float* t0    = (float*)alloc((size_t)M * 32 * 4);
    float* t1    = (float*)alloc((size_t)M * 32 * 4);
    float* t2    = (float*)alloc((size_t)M * 32 * 4);
    int*   ub    = (int*)alloc((size_t)M * 4);
    int*   vb    = (int*)alloc((size_t)M * 4);
    int*   nb2   = (int*)alloc((size_t)M * 9 * 4);
    int*   grid  = (int*)alloc((size_t)2 * 175 * 50 * 4);
    int*   grid2 = (int*)alloc((size_t)2 * 175 * 50 * 4);
    float* acc   = (float*)alloc((size_t)9 * ACC_STRIDE * 4);
    float* sc    = (float*)alloc((size_t)9 * 128 * 4);
    _Float16* zrow = (_Float16*)alloc(128 * 2);          // zeroed dummy gather row
    // f16 feature streams
    _Float16* fhh = (_Float16*)alloc((size_t)N * 64 * 2);
    _Float16* t0h = (_Float16*)alloc((size_t)M * 32 * 2);
    _Float16* t1h = (_Float16*)alloc((size_t)M * 32 * 2);
    _Float16* t2h = (_Float16*)alloc((size_t)M * 32 * 2);
    // split-f16 weight fragments (hi/lo)
    _Float16* wD1h = (_Float16*)alloc((size_t)55296 * 2);
    _Float16* wD1l = (_Float16*)alloc((size_t)55296 * 2);
    _Float16* wReh = (_Float16*)alloc((size_t)55296 * 2);
    _Float16* wRel = (_Float16*)alloc((size_t)55296 * 2);
    _Float16* wS2h = (_Float16*)alloc((size_t)27648 * 2);
    _Float16* wS2l = (_Float16*)alloc((size_t)27648 * 2);
    _Float16* w21h = (_Float16*)alloc((size_t)9216 * 2);
    _Float16* w21l = (_Float16*)alloc((size_t)9216 * 2);
    _Float16* w22h = (_Float16*)alloc((size_t)9216 * 2);
    _Float16* w22l = (_Float16*)alloc((size_t)9216 * 2);
    _Float16* wS3h = (_Float16*)alloc((size_t)27648 * 2);
    _Float16* wS3l = (_Float16*)alloc((size_t)27648 * 2);
    _Float16* wI4h = (_Float16*)alloc((size_t)55296 * 2);
    _Float16* wI4l = (_Float16*)alloc((size_t)55296 * 2);
    float* g0 = (float*)d_out; // N*64 stream computed in the output buffer

    const int accN = 9 * ACC_STRIDE;
    init_kernel<<<(accN + 255) / 256, 256, 0, stream>>>(acc, accN, zrow, grid, 17500);

    // weight split/re-layout, one launch
    WArgs wa;
    auto mkd = [](const float* W, _Float16* H, _Float16* L, int K, int CIN, int COUT, int base) {
        WDesc d; d.W = W; d.H = H; d.L = L; d.K = K; d.CIN = CIN; d.COUT = COUT; d.base = base;
        return d;
    };
    int b0 = 0;
    wa.d[0] = mkd(Wd1,   wD1h, wD1l, 27, 64, 32, b0); b0 += 27 * 64 * 32 / 8;
    wa.d[1] = mkd(Wres,  wReh, wRel, 27, 64, 32, b0); b0 += 27 * 64 * 32 / 8;
    wa.d[2] = mkd(Wsub2, wS2h, wS2l, 27, 32, 32, b0); b0 += 27 * 32 * 32 / 8;
    wa.d[3] = mkd(W2d1,  w21h, w21l,  9, 32, 32, b0); b0 += 9 * 32 * 32 / 8;
    wa.d[4] = mkd(W2d2,  w22h, w22l,  9, 32, 32, b0); b0 += 9 * 32 * 32 / 8;
    wa.d[5] = mkd(Wsub3, wS3h, wS3l, 27, 32, 32, b0); b0 += 27 * 32 * 32 / 8;
    wa.d[6] = mkd(Winv4, wI4h, wI4l, 27, 32, 64, b0); b0 += 27 * 32 * 64 / 8;
    wa.total = b0;
    wsplit_all_kernel<<<(wa.total + 255) / 256, 256, 0, stream>>>(wa);

    // input feats -> f16
    const long totF = (long)N * 64;
    tof16_kernel<<<(int)((totF / 8 + 255) / 256), 256, 0, stream>>>(feats, fhh, totF);

    const int  gT    = (M + 127) / 128;  // 128 rows/block (4 waves x 32 rows)
    const int  gTN   = (N + 127) / 128;
    const long tot32 = (long)M * 32;
    const long tot64 = (long)N * 64;
    const int  ab32  = min((int)((tot32 / 8 + 255) / 256), 2560);
    const int  ab64  = min((int)((tot64 / 8 + 255) / 256), 2560);
    const int  gM    = (M + 255) / 256;

    // stage 1: down1 + res share gathers (dual), stats fused (acc0, acc1)
    gconv_mfma_kernel<64, 32, 27, true><<<gT, 256, 0, stream>>>(
        fhh, nbrD, wD1h, wD1l, wReh, wRel, zrow, t0, t1, acc + 0 * ACC_STRIDE, acc + 1 * ACC_STRIDE, M);
    finalize_kernel<32><<<1, 64, 0, stream>>>(acc + 0 * ACC_STRIDE, bn32g + 0 * 32, bn32b + 0 * 32, M, sc + 0 * 128);
    finalize_kernel<32><<<1, 64, 0, stream>>>(acc + 1 * ACC_STRIDE, bn32g + 2 * 32, bn32b + 2 * 32, M, sc + 1 * 128);
    apply_kernel<32><<<ab32, 256, 0, stream>>>(t0, sc + 0 * 128, nullptr, nullptr, t0h, nullptr, tot32, 1); // d3a -> halves
    apply_kernel<32><<<ab32, 256, 0, stream>>>(t1, sc + 1 * 128, nullptr, t1, nullptr, nullptr, tot32, 1);  // res -> f32

    // stage 2: sub2 -> t2 (stats acc2); d3 = relu(bn)+res -> t2 f32 + halves
    gconv_mfma_kernel<32, 32, 27, false><<<gT, 256, 0, stream>>>(
        t0h, nbrS, wS2h, wS2l, nullptr, nullptr, zrow, t2, nullptr, acc + 2 * ACC_STRIDE, nullptr, M);
    finalize_kernel<32><<<1, 64, 0, stream>>>(acc + 2 * ACC_STRIDE, bn32g + 1 * 32, bn32b + 1 * 32, M, sc + 2 * 128);
    apply_kernel<32><<<ab32, 256, 0, stream>>>(t2, sc + 2 * 128, t1, t2, t2h, nullptr, tot32, 1);

    // 2D neighbor construction (dedup'd atomics; grid laundered for nbr2d)
    uv_scatter_kernel<<<gM, 256, 0, stream>>>(down, l2r, p2c, M, ub, vb, grid);
    grid_copy_kernel<<<(17500 + 255) / 256, 256, 0, stream>>>(grid, grid2, 17500);
    nbr2d_kernel<<<gM, 256, 0, stream>>>(down, ub, vb, grid2, nb2, M);

    // 2d conv 1 -> t0 (stats acc3) -> halves
    gconv_mfma_kernel<32, 32, 9, false><<<gT, 256, 0, stream>>>(
        t2h, nb2, w21h, w21l, nullptr, nullptr, zrow, t0, nullptr, acc + 3 * ACC_STRIDE, nullptr, M);
    finalize_kernel<32><<<1, 64, 0, stream>>>(acc + 3 * ACC_STRIDE, bn32g + 3 * 32, bn32b + 3 * 32, M, sc + 3 * 128);
    apply_kernel<32><<<ab32, 256, 0, stream>>>(t0, sc + 3 * 128, nullptr, nullptr, t0h, nullptr, tot32, 1);

    // 2d conv 2 -> t1 (stats acc4); t1 = relu(bn(t1)) + t2 (stats acc5)
    gconv_mfma_kernel<32, 32, 9, false><<<gT, 256, 0, stream>>>(
        t0h, nb2, w22h, w22l, nullptr, nullptr, zrow, t1, nullptr, acc + 4 * ACC_STRIDE, nullptr, M);
    finalize_kernel<32><<<1, 64, 0, stream>>>(acc + 4 * ACC_STRIDE, bn32g + 4 * 32, bn32b + 4 * 32, M, sc + 4 * 128);
    apply_kernel<32><<<ab32, 256, 0, stream>>>(t1, sc + 4 * 128, t2, t1, nullptr, acc + 5 * ACC_STRIDE, tot32, 1);
    finalize_kernel<32><<<1, 64, 0, stream>>>(acc + 5 * ACC_STRIDE, bn32g + 5 * 32, bn32b + 5 * 32, M, sc + 5 * 128);
    // bn only -> halves for sub3
    apply_kernel<32><<<ab32, 256, 0, stream>>>(t1, sc + 5 * 128, nullptr, nullptr, t1h, nullptr, tot32, 0);

    // sub3 -> t0 (stats acc6) -> halves
    gconv_mfma_kernel<32, 32, 27, false><<<gT, 256, 0, stream>>>(
        t1h, nbrS, wS3h, wS3l, nullptr, nullptr, zrow, t0, nullptr, acc + 6 * ACC_STRIDE, nullptr, M);
    finalize_kernel<32><<<1, 64, 0, stream>>>(acc + 6 * ACC_STRIDE, bn32g + 6 * 32, bn32b + 6 * 32, M, sc + 6 * 128);
    apply_kernel<32><<<ab32, 256, 0, stream>>>(t0, sc + 6 * 128, nullptr, nullptr, t0h, nullptr, tot32, 1);

    // inv4 (N rows) -> d_out (stats acc7); out2 = relu(bn) + feats (stats acc8)
    gconv_mfma_kernel<32, 64, 27, false><<<gTN, 256, 0, stream>>>(
        t0h, nbrI, wI4h, wI4l, nullptr, nullptr, zrow, g0, nullptr, acc + 7 * ACC_STRIDE, nullptr, N);
    finalize_kernel<64><<<1, 64, 0, stream>>>(acc + 7 * ACC_STRIDE, bn64g + 0 * 64, bn64b + 0 * 64, N, sc + 7 * 128);
    apply_kernel<64><<<ab64, 256, 0, stream>>>(g0, sc + 7 * 128, feats, g0, nullptr, acc + 8 * ACC_STRIDE, tot64, 1);
    finalize_kernel<64><<<1, 64, 0, stream>>>(acc + 8 * ACC_STRIDE, bn64g + 1 * 64, bn64b + 1 * 64, N, sc + 8 * 128);
    apply_kernel<64><<<ab64, 256, 0, stream>>>(g0, sc + 8 * 128, nullptr, (float*)d_out, nullptr, nullptr, tot64, 0);
}